// Round 3
// baseline (1287.136 us; speedup 1.0000x reference)
//
#include <hip/hip_runtime.h>
#include <stdint.h>

#define NB 16
#define TQ 1369
#define TS 5476
#define DD 768

#define BM 128
#define BN 128
#define BK 32
#define LDP 40        // row stride in ushorts (80 B = 5x16B granules, odd -> b128 conflict-free)
#define TPU (128*LDP) // ushorts per tile (128 rows x 40)
#define RBQ 11        // query row-blocks per n  (11*128 = 1408 >= 1369)
#define RBS 43        // support row-blocks per n (43*128 = 5504 >= 5476)
#define KB  24        // k-blocks (768/32)
#define QPAD 1408
#define SPAD 5504

typedef float f32x4 __attribute__((ext_vector_type(4)));
typedef short short8 __attribute__((ext_vector_type(8)));
typedef unsigned short ushort;
typedef unsigned long long ull;

// ---------- helpers ----------

__device__ inline float waveReduceSum(float v) {
    #pragma unroll
    for (int m = 32; m >= 1; m >>= 1) v += __shfl_xor(v, m);
    return v;
}

// pack high-16s of two fp32 -> one dword: [a.hi16 : b.hi16] (b lands in low half)
__device__ inline unsigned perm_hi16(unsigned a, unsigned b) {
    return __builtin_amdgcn_perm(a, b, 0x07060302u);
}

// residual (x - trunc_bf16(x)) rounded-half-up to bf16, bits pre-shift (take hi16 via perm)
__device__ inline unsigned lo_rb(float x) {
    unsigned xb = __float_as_uint(x);
    float hi = __uint_as_float(xb & 0xFFFF0000u);
    return __float_as_uint(x - hi) + 0x8000u;
}

__device__ inline f32x4 mfma16(short8 a, short8 b, f32x4 c) {
    return __builtin_amdgcn_mfma_f32_16x16x32_bf16(a, b, c, 0, 0, 0);
}

// async 16B/lane global->LDS DMA (wave-uniform LDS base + lane*16)
__device__ inline void async16(const void* g, void* l) {
    __builtin_amdgcn_global_load_lds(
        (const __attribute__((address_space(1))) unsigned*)g,
        (__attribute__((address_space(3))) unsigned*)l, 16, 0, 0);
}

// ---------- kernel: cls = l2norm(mean over shots) ----------

__global__ __launch_bounds__(256) void cls_kernel(const float* __restrict__ xc,
                                                  float* __restrict__ cls) {
    int n = blockIdx.x, tid = threadIdx.x;
    const float* base = xc + (size_t)n * 4 * DD;
    float v[3]; float ss = 0.f;
    #pragma unroll
    for (int i = 0; i < 3; i++) {
        int e = tid + i * 256;
        float a = base[e] + base[DD + e] + base[2 * DD + e] + base[3 * DD + e];
        v[i] = a * 0.25f; ss += v[i] * v[i];
    }
    ss = waveReduceSum(ss);
    __shared__ float red[4]; __shared__ float rn;
    if ((tid & 63) == 0) red[tid >> 6] = ss;
    __syncthreads();
    if (tid == 0) {
        float t = red[0] + red[1] + red[2] + red[3];
        rn = 1.0f / fmaxf(sqrtf(t), 1e-12f);
    }
    __syncthreads();
    float r = rn;
    #pragma unroll
    for (int i = 0; i < 3; i++) cls[(size_t)n * DD + tid + i * 256] = v[i] * r;
}

// ---------- PATH A: split pass — normalized hi/lo bf16, tiled+padded layout ----------
// layout per matrix: [n][row_block][k_block][128][40] ushort; data in cols 0..31, pad 32..39

__global__ __launch_bounds__(256) void split_kernel(const float* __restrict__ Q,
                                                    const float* __restrict__ S,
                                                    ushort* __restrict__ Qh, ushort* __restrict__ Ql,
                                                    ushort* __restrict__ Sh, ushort* __restrict__ Sl,
                                                    float* __restrict__ rq, float* __restrict__ rs) {
    int wid = (int)((blockIdx.x * 256u + threadIdx.x) >> 6);
    int lane = threadIdx.x & 63;
    bool isQ = wid < NB * QPAD;
    int n, row, nreal;
    ushort *oh, *ol;
    if (isQ) { n = wid / QPAD; row = wid % QPAD; nreal = TQ; }
    else     { int w2 = wid - NB * QPAD; n = w2 / SPAD; row = w2 % SPAD; nreal = TS; }
    int rb = row >> 7, p = row & 127;
    size_t tbase = isQ ? (size_t)(n * RBQ + rb) * KB * TPU
                       : (size_t)(n * RBS + rb) * KB * TPU;
    oh = (isQ ? Qh : Sh) + tbase + p * LDP;
    ol = (isQ ? Ql : Sl) + tbase + p * LDP;

    if (row >= nreal) {                 // zero pad rows (ws is poisoned 0xAA)
        if (lane < 10) {
            uint2 z = {0u, 0u};
            #pragma unroll
            for (int kb = 0; kb < KB; kb++) {
                *(uint2*)(oh + (size_t)kb * TPU + lane * 4) = z;
                *(uint2*)(ol + (size_t)kb * TPU + lane * 4) = z;
            }
        }
        return;
    }

    const float* src = isQ ? Q + ((size_t)n * TQ + row) * DD
                           : S + ((size_t)n * TS + row) * DD;
    float4 x[3]; float ss = 0.f;
    #pragma unroll
    for (int i = 0; i < 3; i++) {
        x[i] = ((const float4*)src)[lane + i * 64];
        ss += x[i].x * x[i].x + x[i].y * x[i].y + x[i].z * x[i].z + x[i].w * x[i].w;
    }
    ss = waveReduceSum(ss);
    float r = 1.0f / fmaxf(sqrtf(ss), 1e-12f);
    if (lane == 0) {
        if (isQ) rq[n * TQ + row] = r; else rs[n * TS + row] = r;
    }
    #pragma unroll
    for (int i = 0; i < 3; i++) {
        float4 a;
        a.x = x[i].x * r; a.y = x[i].y * r; a.z = x[i].z * r; a.w = x[i].w * r;
        int k = lane * 4 + i * 256;
        int kb = k >> 5, off = k & 31;
        unsigned ax = __float_as_uint(a.x), ay = __float_as_uint(a.y);
        unsigned az = __float_as_uint(a.z), aw = __float_as_uint(a.w);
        uint2 h, l;
        h.x = perm_hi16(ay, ax);          h.y = perm_hi16(aw, az);
        l.x = perm_hi16(lo_rb(a.y), lo_rb(a.x)); l.y = perm_hi16(lo_rb(a.w), lo_rb(a.z));
        *(uint2*)(oh + (size_t)kb * TPU + off) = h;
        *(uint2*)(ol + (size_t)kb * TPU + off) = l;
    }
}

// ---------- PATH A: GEMM — DMA staging from tiled split arrays, fused min/argmin ----------

__global__ __launch_bounds__(256, 4) void gemm_a(const ushort* __restrict__ Qh,
                                                 const ushort* __restrict__ Ql,
                                                 const ushort* __restrict__ Sh,
                                                 const ushort* __restrict__ Sl,
                                                 ull* __restrict__ best) {
    __shared__ __align__(16) ushort lds[4][TPU];   // Ah, Al, Bh, Bl — 40,960 B

    int tid = threadIdx.x;
    int w = tid >> 6, lane = tid & 63;
    int bx = blockIdx.x, by = blockIdx.y, n = blockIdx.z;
    int wm = w & 1, wn = w >> 1;
    int g4 = lane >> 4, c16 = lane & 15;

    // wave w stages array w (w is wave-uniform -> scalar selects, no private array)
    size_t tb = (w < 2) ? (size_t)(n * RBQ + bx) * KB * TPU
                        : (size_t)(n * RBS + by) * KB * TPU;
    const ushort* src = (w == 0) ? Qh : (w == 1) ? Ql : (w == 2) ? Sh : Sl;
    const char* gp = (const char*)(src + tb) + lane * 16;

    f32x4 acc[4][4] = {};

    for (int kb = 0; kb < KB; kb++) {
        #pragma unroll
        for (int j = 0; j < 10; j++)
            async16(gp + j * 1024, (char*)&lds[w][0] + j * 1024);
        gp += TPU * 2;
        __syncthreads();

        short8 ah[4], al[4], bh[4], bl[4];
        #pragma unroll
        for (int i = 0; i < 4; i++) {
            int ar = wm * 64 + i * 16 + c16;
            ah[i] = *(const short8*)&lds[0][ar * LDP + g4 * 8];
            al[i] = *(const short8*)&lds[1][ar * LDP + g4 * 8];
            int br = wn * 64 + i * 16 + c16;
            bh[i] = *(const short8*)&lds[2][br * LDP + g4 * 8];
            bl[i] = *(const short8*)&lds[3][br * LDP + g4 * 8];
        }
        #pragma unroll
        for (int mi = 0; mi < 4; mi++)
            #pragma unroll
            for (int ni = 0; ni < 4; ni++) {
                acc[mi][ni] = mfma16(ah[mi], bh[ni], acc[mi][ni]);
                acc[mi][ni] = mfma16(ah[mi], bl[ni], acc[mi][ni]);
                acc[mi][ni] = mfma16(al[mi], bh[ni], acc[mi][ni]);
            }
        __syncthreads();
    }

    // epilogue: d = 1 - dot ; row-wise min+argmin ; packed atomicMin
    int cols[4];
    #pragma unroll
    for (int ni = 0; ni < 4; ni++) cols[ni] = by * BN + wn * 64 + ni * 16 + c16;
    ull* bestn = best + (size_t)n * TQ;

    #pragma unroll
    for (int mi = 0; mi < 4; mi++) {
        int rowb = bx * BM + wm * 64 + mi * 16 + g4 * 4;
        #pragma unroll
        for (int r = 0; r < 4; r++) {
            float dv = 1e30f; int di = 0x7FFFFFFF;
            #pragma unroll
            for (int ni = 0; ni < 4; ni++) {
                float d = 1.0f - acc[mi][ni][r];
                float dd = (cols[ni] < TS) ? d : 1e30f;
                int ii = cols[ni];
                if (dd < dv || (dd == dv && ii < di)) { dv = dd; di = ii; }
            }
            #pragma unroll
            for (int mbit = 1; mbit < 16; mbit <<= 1) {
                float od = __shfl_xor(dv, mbit);
                int   oi = __shfl_xor(di, mbit);
                if (od < dv || (od == dv && oi < di)) { dv = od; di = oi; }
            }
            if (c16 == 0 && (rowb + r) < TQ) {
                unsigned u = __float_as_uint(dv);
                unsigned key = (u & 0x80000000u) ? ~u : (u | 0x80000000u);
                ull pk = ((ull)key << 32) | (unsigned)di;
                atomicMin(&bestn[rowb + r], pk);
            }
        }
    }
}

// ---------- PATH B: rnorm + on-the-fly-split GEMM (R1 kernel, b128 LDS fix) ----------

__global__ __launch_bounds__(256) void rnorm_kernel(const float* __restrict__ Q,
                                                    const float* __restrict__ S,
                                                    float* __restrict__ rq,
                                                    float* __restrict__ rs) {
    int wid = (int)((blockIdx.x * 256u + threadIdx.x) >> 6);
    int lane = threadIdx.x & 63;
    const int NQ = NB * TQ, NSr = NB * TS;
    if (wid >= NQ + NSr) return;
    const float* base = (wid < NQ) ? Q + (size_t)wid * DD : S + (size_t)(wid - NQ) * DD;
    float ss = 0.f;
    #pragma unroll
    for (int i = 0; i < 3; i++) {
        float4 x = ((const float4*)base)[lane + i * 64];
        ss += x.x * x.x + x.y * x.y + x.z * x.z + x.w * x.w;
    }
    ss = waveReduceSum(ss);
    if (lane == 0) {
        float r = 1.0f / fmaxf(sqrtf(ss), 1e-12f);
        if (wid < NQ) rq[wid] = r; else rs[wid - NQ] = r;
    }
}

__device__ inline void cvt_store8(ushort* ph, ushort* pl, float4 a, float4 b) {
    unsigned ax = __float_as_uint(a.x), ay = __float_as_uint(a.y);
    unsigned az = __float_as_uint(a.z), aw = __float_as_uint(a.w);
    unsigned bx = __float_as_uint(b.x), by = __float_as_uint(b.y);
    unsigned bz = __float_as_uint(b.z), bw = __float_as_uint(b.w);
    uint4 h, l;
    h.x = perm_hi16(ay, ax); h.y = perm_hi16(aw, az);
    h.z = perm_hi16(by, bx); h.w = perm_hi16(bw, bz);
    l.x = perm_hi16(lo_rb(a.y), lo_rb(a.x)); l.y = perm_hi16(lo_rb(a.w), lo_rb(a.z));
    l.z = perm_hi16(lo_rb(b.y), lo_rb(b.x)); l.w = perm_hi16(lo_rb(b.w), lo_rb(b.z));
    *(uint4*)ph = h;   // single b128 store (16B aligned: row*80 + cc*16)
    *(uint4*)pl = l;
}

__global__ __launch_bounds__(256, 3) void gemm_b(const float* __restrict__ Q,
                                                 const float* __restrict__ S,
                                                 const float* __restrict__ rq,
                                                 const float* __restrict__ rs,
                                                 ull* __restrict__ best) {
    __shared__ __align__(16) ushort Ah[BM * LDP];
    __shared__ __align__(16) ushort Al[BM * LDP];
    __shared__ __align__(16) ushort Bh[BN * LDP];
    __shared__ __align__(16) ushort Bl[BN * LDP];

    int tid = threadIdx.x;
    int bx = blockIdx.x, by = blockIdx.y, n = blockIdx.z;
    const float* Abase = Q + (size_t)n * TQ * DD;
    const float* Bbase = S + (size_t)n * TS * DD;

    int w = tid >> 6, lane = tid & 63;
    int wm = w & 1, wn = w >> 1;
    int g4 = lane >> 4, c16 = lane & 15;

    f32x4 acc[4][4] = {};
    const int arow0 = bx * BM, brow0 = by * BN;

    for (int kt = 0; kt < DD; kt += BK) {
        __syncthreads();
        #pragma unroll
        for (int half = 0; half < 2; half++) {
            int c = tid + half * 256;
            int row = c >> 2, cc = c & 3;
            {
                int grow = min(arow0 + row, TQ - 1);
                const float* p = Abase + (size_t)grow * DD + kt + cc * 8;
                cvt_store8(&Ah[row * LDP + cc * 8], &Al[row * LDP + cc * 8],
                           *(const float4*)p, *(const float4*)(p + 4));
            }
            {
                int grow = min(brow0 + row, TS - 1);
                const float* p = Bbase + (size_t)grow * DD + kt + cc * 8;
                cvt_store8(&Bh[row * LDP + cc * 8], &Bl[row * LDP + cc * 8],
                           *(const float4*)p, *(const float4*)(p + 4));
            }
        }
        __syncthreads();

        short8 ah[4], al[4], bh[4], bl[4];
        #pragma unroll
        for (int i = 0; i < 4; i++) {
            int ar = wm * 64 + i * 16 + c16;
            ah[i] = *(const short8*)&Ah[ar * LDP + g4 * 8];
            al[i] = *(const short8*)&Al[ar * LDP + g4 * 8];
            int br = wn * 64 + i * 16 + c16;
            bh[i] = *(const short8*)&Bh[br * LDP + g4 * 8];
            bl[i] = *(const short8*)&Bl[br * LDP + g4 * 8];
        }
        #pragma unroll
        for (int mi = 0; mi < 4; mi++)
            #pragma unroll
            for (int ni = 0; ni < 4; ni++) {
                acc[mi][ni] = mfma16(ah[mi], bh[ni], acc[mi][ni]);
                acc[mi][ni] = mfma16(ah[mi], bl[ni], acc[mi][ni]);
                acc[mi][ni] = mfma16(al[mi], bh[ni], acc[mi][ni]);
            }
    }

    float rsv[4]; int cols[4];
    #pragma unroll
    for (int ni = 0; ni < 4; ni++) {
        int col = brow0 + wn * 64 + ni * 16 + c16;
        cols[ni] = col;
        rsv[ni] = (col < TS) ? rs[(size_t)n * TS + col] : 0.f;
    }
    const float* rqn = rq + (size_t)n * TQ;
    ull* bestn = best + (size_t)n * TQ;

    #pragma unroll
    for (int mi = 0; mi < 4; mi++) {
        int rowb = arow0 + wm * 64 + mi * 16 + g4 * 4;
        float rq4[4];
        #pragma unroll
        for (int r = 0; r < 4; r++) {
            int qr = rowb + r;
            rq4[r] = (qr < TQ) ? rqn[qr] : 0.f;
        }
        #pragma unroll
        for (int r = 0; r < 4; r++) {
            float dv = 1e30f; int di = 0x7FFFFFFF;
            #pragma unroll
            for (int ni = 0; ni < 4; ni++) {
                float m = acc[mi][ni][r] * rsv[ni];
                float d = 1.0f - rq4[r] * m;
                float dd = (cols[ni] < TS) ? d : 1e30f;
                int ii = cols[ni];
                if (dd < dv || (dd == dv && ii < di)) { dv = dd; di = ii; }
            }
            #pragma unroll
            for (int mbit = 1; mbit < 16; mbit <<= 1) {
                float od = __shfl_xor(dv, mbit);
                int   oi = __shfl_xor(di, mbit);
                if (od < dv || (od == dv && oi < di)) { dv = od; di = oi; }
            }
            if (c16 == 0 && (rowb + r) < TQ) {
                unsigned u = __float_as_uint(dv);
                unsigned key = (u & 0x80000000u) ? ~u : (u | 0x80000000u);
                ull pk = ((ull)key << 32) | (unsigned)di;
                atomicMin(&bestn[rowb + r], pk);
            }
        }
    }
}

// ---------- head: gather nearest, linear + sigmoid ----------

__global__ __launch_bounds__(256) void head_kernel(const float* __restrict__ Q,
                                                   const float* __restrict__ S,
                                                   const float* __restrict__ rq,
                                                   const float* __restrict__ rs,
                                                   const float* __restrict__ cls,
                                                   const float* __restrict__ W,
                                                   const float* __restrict__ bb,
                                                   const ull* __restrict__ best,
                                                   float* __restrict__ out) {
    int wid = (int)((blockIdx.x * 256u + threadIdx.x) >> 6);
    int lane = threadIdx.x & 63;
    if (wid >= NB * TQ) return;
    int n = wid / TQ;
    ull pk = best[wid];
    unsigned key = (unsigned)(pk >> 32);
    int idx = (int)(unsigned)(pk & 0xFFFFFFFFu);
    unsigned ub = (key & 0x80000000u) ? (key ^ 0x80000000u) : ~key;
    float dmin = __uint_as_float(ub);

    const float* qrow = Q + (size_t)wid * DD;
    const float* srow = S + ((size_t)n * TS + idx) * DD;
    const float* clsr = cls + (size_t)n * DD;
    float sq = 0.f, ssum = 0.f, sc = 0.f;
    #pragma unroll
    for (int i = 0; i < 12; i++) {
        int j = lane + i * 64;
        sq   += qrow[j] * W[j];
        ssum += srow[j] * W[DD + j];
        sc   += clsr[j] * W[2 * DD + j];
    }
    float tot = sq * rq[wid] + ssum * rs[(size_t)n * TS + idx] + sc;
    tot = waveReduceSum(tot);
    if (lane == 0) {
        float logit = tot + bb[0];
        float pred = 1.0f / (1.0f + expf(-logit));
        out[wid] = pred * dmin;
        out[NB * TQ + wid] = pred;
    }
}

// ---------- launch ----------

extern "C" void kernel_launch(void* const* d_in, const int* in_sizes, int n_in,
                              void* d_out, int out_size, void* d_ws, size_t ws_size,
                              hipStream_t stream) {
    const float* Q  = (const float*)d_in[0];
    const float* S  = (const float*)d_in[1];
    const float* XC = (const float*)d_in[2];
    const float* W  = (const float*)d_in[3];
    const float* B  = (const float*)d_in[4];
    (void)in_sizes; (void)n_in; (void)out_size;

    char* ws = (char*)d_ws;
    ull*   best = (ull*)ws;                          // 175,232 B
    float* rq   = (float*)(ws + 175232);             //  87,616 B
    float* rs   = (float*)(ws + 262848);             // 350,464 B
    float* cls  = (float*)(ws + 613312);             //  49,152 B
    // tiled split arrays (path A)
    ushort* Qh = (ushort*)(ws + 663552);             //  43,253,760 B
    ushort* Ql = (ushort*)(ws + 663552 + 43253760ull);
    ushort* Sh = (ushort*)(ws + 663552 + 2*43253760ull);
    ushort* Sl = (ushort*)(ws + 663552 + 2*43253760ull + 169082880ull);
    const size_t NEED = 663552ull + 2*43253760ull + 2*169082880ull;   // 425,336,832

    hipMemsetAsync(best, 0xFF, (size_t)NB * TQ * 8, stream);
    cls_kernel<<<NB, 256, 0, stream>>>(XC, cls);

    dim3 grid((TQ + BM - 1) / BM, (TS + BN - 1) / BN, NB);   // (11, 43, 16)

    if (ws_size >= NEED) {
        // PATH A: precomputed normalized hi/lo split + DMA-staged GEMM
        int waves = NB * QPAD + NB * SPAD;                   // 110,592
        split_kernel<<<waves / 4, 256, 0, stream>>>(Q, S, Qh, Ql, Sh, Sl, rq, rs);
        gemm_a<<<grid, 256, 0, stream>>>(Qh, Ql, Sh, Sl, best);
    } else {
        // PATH B: on-the-fly split (R1 structure, b128 LDS fix)
        int rn_rows = NB * TQ + NB * TS;                     // 109,520
        rnorm_kernel<<<rn_rows / 4, 256, 0, stream>>>(Q, S, rq, rs);
        gemm_b<<<grid, 256, 0, stream>>>(Q, S, rq, rs, best);
    }

    head_kernel<<<(NB * TQ) / 4, 256, 0, stream>>>(Q, S, rq, rs, cls, W, B, best, (float*)d_out);
}

// Round 4
// 849.652 us; speedup vs baseline: 1.5149x; 1.5149x over previous
//
#include <hip/hip_runtime.h>
#include <stdint.h>

#define NB 16
#define TQ 1369
#define TS 5476
#define DD 768

#define BM 128
#define BN 128
#define KB 24          // k-blocks of 32 (768/32)
#define RBQ 11         // query row-blocks per n  (11*128 = 1408)
#define RBS 43         // support row-blocks per n (43*128 = 5504)
#define QPAD 1408
#define SPAD 5504
#define DSTR 5632      // dist row stride in fp16 elems = 11*512 (exact b128 scan)
#define EPS_SEL 2.5e-3f

typedef float f32x4 __attribute__((ext_vector_type(4)));
typedef short short8 __attribute__((ext_vector_type(8)));
typedef unsigned short ushort;

// ---------- helpers ----------

__device__ inline float waveReduceSum(float v) {
    #pragma unroll
    for (int m = 32; m >= 1; m >>= 1) v += __shfl_xor(v, m);
    return v;
}

// fp32 -> bf16 with round-to-nearest-even, returns low 16 bits
__device__ inline unsigned bf16rne(float x) {
    unsigned u = __float_as_uint(x);
    return (u + 0x7FFFu + ((u >> 16) & 1u)) >> 16;
}
__device__ inline unsigned pack2(float lo, float hi) {
    return bf16rne(lo) | (bf16rne(hi) << 16);
}

__device__ inline f32x4 mfma16(short8 a, short8 b, f32x4 c) {
    return __builtin_amdgcn_mfma_f32_16x16x32_bf16(a, b, c, 0, 0, 0);
}

// async 16B/lane global->LDS DMA (wave-uniform LDS base + lane*16)
__device__ inline void async16(const void* g, void* l) {
    __builtin_amdgcn_global_load_lds(
        (const __attribute__((address_space(1))) unsigned*)g,
        (__attribute__((address_space(3))) unsigned*)l, 16, 0, 0);
}

__device__ inline float h2f(ushort u) {
    union { ushort us; _Float16 h; } cv; cv.us = u;
    return (float)cv.h;
}

// ---------- kernel 1: cls = l2norm(mean over shots) ----------

__global__ __launch_bounds__(256) void cls_kernel(const float* __restrict__ xc,
                                                  float* __restrict__ cls) {
    int n = blockIdx.x, tid = threadIdx.x;
    const float* base = xc + (size_t)n * 4 * DD;
    float v[3]; float ss = 0.f;
    #pragma unroll
    for (int i = 0; i < 3; i++) {
        int e = tid + i * 256;
        float a = base[e] + base[DD + e] + base[2 * DD + e] + base[3 * DD + e];
        v[i] = a * 0.25f; ss += v[i] * v[i];
    }
    ss = waveReduceSum(ss);
    __shared__ float red[4]; __shared__ float rn;
    if ((tid & 63) == 0) red[tid >> 6] = ss;
    __syncthreads();
    if (tid == 0) {
        float t = red[0] + red[1] + red[2] + red[3];
        rn = 1.0f / fmaxf(sqrtf(t), 1e-12f);
    }
    __syncthreads();
    float r = rn;
    #pragma unroll
    for (int i = 0; i < 3; i++) cls[(size_t)n * DD + tid + i * 256] = v[i] * r;
}

// ---------- kernel 2: normalized bf16 (RNE), dense tiled [n][rb][kb][g][128][8] ----------
// tile = 4096 ushorts (8192 B): 4 kgroups x 128 rows x 8 elems -> 16-lane-contiguous frag reads

__global__ __launch_bounds__(256) void split_kernel(const float* __restrict__ Q,
                                                    const float* __restrict__ S,
                                                    ushort* __restrict__ Qh,
                                                    ushort* __restrict__ Sh,
                                                    float* __restrict__ rq,
                                                    float* __restrict__ rs) {
    int wid = (int)((blockIdx.x * 256u + threadIdx.x) >> 6);
    int lane = threadIdx.x & 63;
    bool isQ = wid < NB * QPAD;
    int n, row, nreal;
    if (isQ) { n = wid / QPAD; row = wid % QPAD; nreal = TQ; }
    else     { int w2 = wid - NB * QPAD; n = w2 / SPAD; row = w2 % SPAD; nreal = TS; }
    int rb = row >> 7, p = row & 127;
    size_t tbase = isQ ? (size_t)(n * RBQ + rb) * KB * 4096
                       : (size_t)(n * RBS + rb) * KB * 4096;
    ushort* outp = (isQ ? Qh : Sh) + tbase;

    if (row >= nreal) {                 // zero pad rows (ws is poisoned 0xAA)
        uint4 z = {0u, 0u, 0u, 0u};
        for (int t = lane; t < 96; t += 64) {
            int kb = t >> 2, g = t & 3;
            *(uint4*)(outp + (size_t)kb * 4096 + g * 1024 + p * 8) = z;
        }
        return;
    }

    const float* src = isQ ? Q + ((size_t)n * TQ + row) * DD
                           : S + ((size_t)n * TS + row) * DD;
    float4 x[3]; float ss = 0.f;
    #pragma unroll
    for (int i = 0; i < 3; i++) {
        x[i] = ((const float4*)src)[lane + i * 64];
        ss += x[i].x * x[i].x + x[i].y * x[i].y + x[i].z * x[i].z + x[i].w * x[i].w;
    }
    ss = waveReduceSum(ss);
    float r = 1.0f / fmaxf(sqrtf(ss), 1e-12f);
    if (lane == 0) {
        if (isQ) rq[(size_t)n * TQ + row] = r; else rs[(size_t)n * TS + row] = r;
    }
    #pragma unroll
    for (int i = 0; i < 3; i++) {
        float ax = x[i].x * r, ay = x[i].y * r, az = x[i].z * r, aw = x[i].w * r;
        int k0 = lane * 4 + i * 256;
        int kb = k0 >> 5;
        int g  = (k0 >> 3) & 3;
        int sub = k0 & 7;               // 0 or 4
        uint2 hv;
        hv.x = pack2(ax, ay);
        hv.y = pack2(az, aw);
        *(uint2*)(outp + (size_t)kb * 4096 + g * 1024 + p * 8 + sub) = hv;
    }
}

// ---------- kernel 3: single-term bf16 GEMM, fp16 dot matrix out ----------

__global__ __launch_bounds__(256, 4) void gemm1(const ushort* __restrict__ Qh,
                                                const ushort* __restrict__ Sh,
                                                ushort* __restrict__ dist) {
    __shared__ __align__(16) ushort As[4096];   // 8 KB
    __shared__ __align__(16) ushort Bs[4096];   // 8 KB

    int tid = threadIdx.x, w = tid >> 6, lane = tid & 63;
    int bx = blockIdx.x, by = blockIdx.y, n = blockIdx.z;
    int wm = w & 1, wn = w >> 1, g4 = lane >> 4, c16 = lane & 15;

    // waves 0,1 stage A halves; 2,3 stage B halves
    const char* gsrc = (const char*)((w < 2)
        ? (Qh + (size_t)(n * RBQ + bx) * KB * 4096)
        : (Sh + (size_t)(n * RBS + by) * KB * 4096)) + (w & 1) * 4096 + lane * 16;
    char* lbase = (char*)((w < 2) ? As : Bs) + (w & 1) * 4096;

    f32x4 acc[4][4] = {};
    int aoff = g4 * 1024 + wm * 512 + c16 * 8;
    int boff = g4 * 1024 + wn * 512 + c16 * 8;

    for (int kb = 0; kb < KB; kb++) {
        #pragma unroll
        for (int j = 0; j < 4; j++)
            async16(gsrc + (size_t)kb * 8192 + j * 1024, lbase + j * 1024);
        __syncthreads();

        short8 ah[4], bh[4];
        #pragma unroll
        for (int i = 0; i < 4; i++) {
            ah[i] = *(const short8*)&As[aoff + i * 128];
            bh[i] = *(const short8*)&Bs[boff + i * 128];
        }
        #pragma unroll
        for (int mi = 0; mi < 4; mi++)
            #pragma unroll
            for (int ni = 0; ni < 4; ni++)
                acc[mi][ni] = mfma16(ah[mi], bh[ni], acc[mi][ni]);
        __syncthreads();
    }

    // epilogue: store fp16 dots (cols >= TS are pad-garbage, masked in select)
    int row0 = bx * BM + wm * 64 + g4 * 4;
    int col0 = by * BN + wn * 64 + c16;
    #pragma unroll
    for (int mi = 0; mi < 4; mi++) {
        #pragma unroll
        for (int r = 0; r < 4; r++) {
            int rowq = row0 + mi * 16 + r;
            if (rowq < TQ) {
                ushort* dp = dist + (size_t)(n * TQ + rowq) * DSTR + col0;
                #pragma unroll
                for (int ni = 0; ni < 4; ni++) {
                    union { _Float16 h; ushort u; } cv;
                    cv.h = (_Float16)acc[mi][ni][r];
                    dp[ni * 16] = cv.u;
                }
            }
        }
    }
}

// ---------- kernel 4: select (approx scan + exact verify) + head, one wave/query ----------

__global__ __launch_bounds__(256) void select_head(const ushort* __restrict__ dist,
                                                   const float* __restrict__ Q,
                                                   const float* __restrict__ S,
                                                   const float* __restrict__ rq,
                                                   const float* __restrict__ rs,
                                                   const float* __restrict__ cls,
                                                   const float* __restrict__ W,
                                                   const float* __restrict__ bb,
                                                   float* __restrict__ out) {
    __shared__ int cand[4][32];
    __shared__ int ccnt[4];
    int w = threadIdx.x >> 6, lane = threadIdx.x & 63;
    int qi = blockIdx.x * 4 + w;                   // 5476*4 = 21904 exactly
    int n = qi / TQ;
    const ushort* rowp = dist + (size_t)qi * DSTR;

    // pass 1: approx max-dot (first-index ties)
    float pm = -1e30f; int im = 0x7FFFFFFF;
    #pragma unroll
    for (int it = 0; it < 11; it++) {
        union { uint4 v; ushort us[8]; } u;
        u.v = *(const uint4*)(rowp + it * 512 + lane * 8);
        int col0 = it * 512 + lane * 8;
        #pragma unroll
        for (int e = 0; e < 8; e++) {
            float p = h2f(u.us[e]);
            int col = col0 + e;
            if (col < TS && p > pm) { pm = p; im = col; }
        }
    }
    #pragma unroll
    for (int m = 1; m < 64; m <<= 1) {
        float op = __shfl_xor(pm, m);
        int   oi = __shfl_xor(im, m);
        if (op > pm || (op == pm && oi < im)) { pm = op; im = oi; }
    }

    // pass 2: collect candidates within EPS of approx max
    if (lane == 0) ccnt[w] = 0;
    float thresh = pm - EPS_SEL;
    #pragma unroll
    for (int it = 0; it < 11; it++) {
        union { uint4 v; ushort us[8]; } u;
        u.v = *(const uint4*)(rowp + it * 512 + lane * 8);
        int col0 = it * 512 + lane * 8;
        #pragma unroll
        for (int e = 0; e < 8; e++) {
            float p = h2f(u.us[e]);
            int col = col0 + e;
            if (col < TS && p >= thresh) {
                int slot = atomicAdd(&ccnt[w], 1);
                if (slot < 32) cand[w][slot] = col;
            }
        }
    }
    int cnt = min(ccnt[w], 32);

    // exact fp32 re-check of candidates (deterministic, first-index ties)
    const float* qrow = Q + (size_t)qi * DD;
    float4 q4[3];
    #pragma unroll
    for (int i = 0; i < 3; i++) q4[i] = ((const float4*)qrow)[lane + i * 64];
    float rqv = rq[qi];

    float bestd = -1e30f; int bidx = 0x7FFFFFFF;
    for (int c = 0; c < cnt; c++) {
        int sidx = cand[w][c];
        const float* srow = S + ((size_t)n * TS + sidx) * DD;
        float part = 0.f;
        #pragma unroll
        for (int i = 0; i < 3; i++) {
            float4 s4 = ((const float4*)srow)[lane + i * 64];
            part += q4[i].x * s4.x + q4[i].y * s4.y + q4[i].z * s4.z + q4[i].w * s4.w;
        }
        part = waveReduceSum(part);                 // bit-identical on all lanes
        float dot = part * rqv * rs[(size_t)n * TS + sidx];
        if (dot > bestd || (dot == bestd && sidx < bidx)) { bestd = dot; bidx = sidx; }
    }
    float dmin = 1.0f - bestd;

    // head: sigmoid(q_n·W0 + s_n·W1 + cls·W2 + b)
    const float* srow = S + ((size_t)n * TS + bidx) * DD;
    const float* clsr = cls + (size_t)n * DD;
    float rsv = rs[(size_t)n * TS + bidx];
    float aq = 0.f, as_ = 0.f, ac = 0.f;
    #pragma unroll
    for (int i = 0; i < 3; i++) {
        float4 s4 = ((const float4*)srow)[lane + i * 64];
        float4 c4 = ((const float4*)clsr)[lane + i * 64];
        float4 w0 = ((const float4*)W)[lane + i * 64];
        float4 w1 = ((const float4*)(W + DD))[lane + i * 64];
        float4 w2 = ((const float4*)(W + 2 * DD))[lane + i * 64];
        aq += q4[i].x * w0.x + q4[i].y * w0.y + q4[i].z * w0.z + q4[i].w * w0.w;
        as_ += s4.x * w1.x + s4.y * w1.y + s4.z * w1.z + s4.w * w1.w;
        ac += c4.x * w2.x + c4.y * w2.y + c4.z * w2.z + c4.w * w2.w;
    }
    float tot = waveReduceSum(aq * rqv + as_ * rsv + ac);
    if (lane == 0) {
        float logit = tot + bb[0];
        float pred = 1.0f / (1.0f + expf(-logit));
        out[qi] = pred * dmin;
        out[NB * TQ + qi] = pred;
    }
}

// ---------- launch ----------

extern "C" void kernel_launch(void* const* d_in, const int* in_sizes, int n_in,
                              void* d_out, int out_size, void* d_ws, size_t ws_size,
                              hipStream_t stream) {
    const float* Q  = (const float*)d_in[0];
    const float* S  = (const float*)d_in[1];
    const float* XC = (const float*)d_in[2];
    const float* W  = (const float*)d_in[3];
    const float* B  = (const float*)d_in[4];
    (void)in_sizes; (void)n_in; (void)out_size;

    char* ws = (char*)d_ws;
    ushort* dist = (ushort*)ws;                                   // 246,726,656 B
    ushort* Qh   = (ushort*)(ws + 246726656ull);                  //  34,603,008 B
    ushort* Sh   = (ushort*)(ws + 246726656ull + 34603008ull);    // 135,266,304 B
    float*  rq   = (float*)(ws + 416595968ull);                   //      87,616 B
    float*  rs   = (float*)(ws + 416683584ull);                   //     350,464 B
    float*  cls  = (float*)(ws + 417034048ull);                   //      49,152 B
    // total 417,083,200 B — ws proven >= 425,336,832 in R3 (path A ran)
    if (ws_size < 417083200ull) return;

    cls_kernel<<<NB, 256, 0, stream>>>(XC, cls);

    // 16*1408 + 16*5504 = 110,592 waves / 4 per block
    split_kernel<<<27648, 256, 0, stream>>>(Q, S, Qh, Sh, rq, rs);

    dim3 grid(RBQ, RBS, NB);                                      // (11, 43, 16)
    gemm1<<<grid, 256, 0, stream>>>(Qh, Sh, dist);

    select_head<<<(NB * TQ) / 4, 256, 0, stream>>>(dist, Q, S, rq, rs, cls, W, B,
                                                   (float*)d_out);
}